// Round 6
// baseline (2435.899 us; speedup 1.0000x reference)
//
#include <hip/hip_runtime.h>

// PointNet++ front-end on MI355X: FPS (B=4, N=16384, NPOINT=1024) + ball query
// nsample=1, radius=0.5. xyz layout [B,3,N]. Output int32 [B,NPOINT,1].
//
// Round-6: algorithmic skipping. Points spatially binned (8^3 grid counting
// sort -> perm); each of 512 threads owns 32 spatially-coherent points in
// registers plus a cached packed argmax key. Per FPS iteration a conservative
// bounding-sphere test skips groups whose min possible distance to the new
// centroid exceeds the group's max dst -- for such groups min(dst,d)==dst
// bit-exactly, so the skip is EXACT. Only active waves rescan.
// Keys: (dst_bits<<32)|(16383-orig_idx): u64 max == (max val, tie -> min
// orig idx) == np.argmax first-occurrence semantics, independent of the
// spatial permutation (keys globally unique).

typedef unsigned long long u64;

constexpr int   N_PTS  = 16384;
constexpr int   NPOINT = 1024;
constexpr int   TB     = 512;          // threads per block (8 waves)
constexpr int   GP     = N_PTS / TB;   // 32 points per thread/group
constexpr int   NWAVE  = TB / 64;      // 8
constexpr float BIGF   = 1e10f;

// Wave-wide u32 max via DPP (canonical 64-lane sequence; bound_ctrl=false
// keeps old value for invalid lanes == identity for max). Structure verified
// bit-exact in rounds 4-5.
__device__ inline unsigned wave_max_u32(unsigned v) {
    int x = (int)v;
    int t;
    t = __builtin_amdgcn_update_dpp(x, x, 0x111, 0xf, 0xf, false);  // row_shr:1
    x = ((unsigned)x > (unsigned)t) ? x : t;
    t = __builtin_amdgcn_update_dpp(x, x, 0x112, 0xf, 0xf, false);  // row_shr:2
    x = ((unsigned)x > (unsigned)t) ? x : t;
    t = __builtin_amdgcn_update_dpp(x, x, 0x114, 0xf, 0xf, false);  // row_shr:4
    x = ((unsigned)x > (unsigned)t) ? x : t;
    t = __builtin_amdgcn_update_dpp(x, x, 0x118, 0xf, 0xf, false);  // row_shr:8
    x = ((unsigned)x > (unsigned)t) ? x : t;
    t = __builtin_amdgcn_update_dpp(x, x, 0x142, 0xa, 0xf, false);  // bcast15
    x = ((unsigned)x > (unsigned)t) ? x : t;
    t = __builtin_amdgcn_update_dpp(x, x, 0x143, 0xc, 0xf, false);  // bcast31
    x = ((unsigned)x > (unsigned)t) ? x : t;
    return (unsigned)__builtin_amdgcn_readlane(x, 63);
}

__device__ inline u64 rdlane64(u64 v, int lane) {
    const int lo = __builtin_amdgcn_readlane((int)(unsigned)(v & 0xFFFFFFFFull), lane);
    const int hi = __builtin_amdgcn_readlane((int)(unsigned)(v >> 32), lane);
    return ((u64)(unsigned)hi << 32) | (unsigned)lo;
}

// ---------------------------------------------------------------------------
// Spatial binning: 8^3 grid counting sort -> perm[b][N]. Order within a cell
// is nondeterministic (atomics) but output of FPS is exact regardless
// (grouping affects only which groups get skipped, never any dst value).
// ---------------------------------------------------------------------------
__global__ __launch_bounds__(TB) void bin_kernel(
    const float* __restrict__ xyz, int* __restrict__ perm)
{
    const int b = blockIdx.x, tid = threadIdx.x;
    const float* X = xyz + (size_t)b * 3 * N_PTS;
    const float* Y = X + N_PTS;
    const float* Z = X + 2 * N_PTS;

    __shared__ int cnt[512];
    __shared__ int tmp[512];
    cnt[tid] = 0;
    __syncthreads();

    int cell[GP];
#pragma unroll
    for (int k = 0; k < GP; ++k) {
        const int p = tid + k * TB;              // strided: coalesced
        const float x = X[p], y = Y[p], z = Z[p];
        int ix = (int)(x * 8.0f); ix = ix > 7 ? 7 : (ix < 0 ? 0 : ix);
        int iy = (int)(y * 8.0f); iy = iy > 7 ? 7 : (iy < 0 ? 0 : iy);
        int iz = (int)(z * 8.0f); iz = iz > 7 ? 7 : (iz < 0 ? 0 : iz);
        cell[k] = (ix << 6) | (iy << 3) | iz;
        atomicAdd(&cnt[cell[k]], 1);
    }
    __syncthreads();

    const int own = cnt[tid];
    tmp[tid] = own;
    __syncthreads();
    for (int s = 1; s < 512; s <<= 1) {          // Hillis-Steele inclusive scan
        const int add = (tid >= s) ? tmp[tid - s] : 0;
        __syncthreads();
        tmp[tid] += add;
        __syncthreads();
    }
    cnt[tid] = tmp[tid] - own;                   // exclusive offsets
    __syncthreads();

#pragma unroll
    for (int k = 0; k < GP; ++k) {
        const int p = tid + k * TB;
        const int pos = atomicAdd(&cnt[cell[k]], 1);
        perm[(size_t)b * N_PTS + pos] = p;
    }
}

// ---------------------------------------------------------------------------
// FPS with group skipping. One block per batch (R3 proved grid sync is ~10x
// a block barrier). amdgpu_waves_per_eu(1): allocator budget up to 512 regs;
// only 4 blocks run on 256 CUs so occupancy is irrelevant.
// ---------------------------------------------------------------------------
__global__ __launch_bounds__(TB)
__attribute__((amdgpu_waves_per_eu(1)))
void fps_group(const float* __restrict__ xyz,
               const int* __restrict__ perm,
               int* __restrict__ cent)
{
#pragma clang fp contract(off)
    const int b    = blockIdx.x;
    const int tid  = threadIdx.x;
    const int wave = tid >> 6;
    const int lane = tid & 63;

    const float* X = xyz + (size_t)b * 3 * N_PTS;
    const float* Y = X + N_PTS;
    const float* Z = X + 2 * N_PTS;
    const int*  pm = perm + (size_t)b * N_PTS + tid * GP;

    float px[GP], py[GP], pz[GP], dst[GP];
    int   inv[GP];                               // 16383 - orig_idx
#pragma unroll
    for (int k = 0; k < GP; ++k) {
        const int o = pm[k];
        px[k] = X[o]; py[k] = Y[o]; pz[k] = Z[o];
        inv[k] = (N_PTS - 1) - o;
        dst[k] = BIGF;
    }

    // conservative group bounding sphere (center arbitrary; radius inflated
    // so it upper-bounds true distances despite fp rounding)
    float mx = 0.0f, my = 0.0f, mz = 0.0f;
#pragma unroll
    for (int k = 0; k < GP; ++k) { mx += px[k]; my += py[k]; mz += pz[k]; }
    mx *= (1.0f / GP); my *= (1.0f / GP); mz *= (1.0f / GP);
    float r2 = 0.0f;
#pragma unroll
    for (int k = 0; k < GP; ++k) {
        const float dx = px[k] - mx, dy = py[k] - my, dz = pz[k] - mz;
        r2 = fmaxf(r2, (dx * dx + dy * dy) + dz * dz);
    }
    const float rg = sqrtf(r2) * 1.0001f + 1e-6f;

    __shared__ u64   s_key[2][NWAVE];
    __shared__ float s_cx[2][NWAVE], s_cy[2][NWAVE], s_cz[2][NWAVE];

    // ---- initial far: global argmax over x via packed keys ----
    int far;
    {
        u64 kx = ((u64)(unsigned)__float_as_uint(px[0]) << 32) | (unsigned)inv[0];
#pragma unroll
        for (int k = 1; k < GP; ++k) {
            const u64 c = ((u64)(unsigned)__float_as_uint(px[k]) << 32) | (unsigned)inv[k];
            if (c > kx) kx = c;
        }
#pragma unroll
        for (int off = 32; off > 0; off >>= 1) {
            const u64 o = __shfl_xor(kx, off);
            if (o > kx) kx = o;
        }
        if (lane == 0) s_key[0][wave] = kx;
        __syncthreads();
        u64 bk = s_key[0][0];
#pragma unroll
        for (int w = 1; w < NWAVE; ++w)
            if (s_key[0][w] > bk) bk = s_key[0][w];
        far = __builtin_amdgcn_readfirstlane((N_PTS - 1) - (int)(bk & 0xFFFFu));
    }
    float cx = X[far], cy = Y[far], cz = Z[far];   // one-time global load

    // cached per-group state: key.hi == group max dst (BIG => active iter 1)
    u64   key = ((u64)(unsigned)__float_as_uint(BIGF) << 32);
    float bx = 0.0f, by = 0.0f, bz = 0.0f;

    for (int it = 0; it < NPOINT; ++it) {
        if (tid == 0) cent[b * NPOINT + it] = far;   // record PRE-update far
        if (it == NPOINT - 1) break;                 // last update unused

        // ---- conservative skip test (margins >> 5-ulp rounding) ----
        const float ddx = cx - mx, ddy = cy - my, ddz = cz - mz;
        const float dcm2 = (ddx * ddx + ddy * ddy) + ddz * ddz;
        const float lb = sqrtf(dcm2) * 0.9999f - rg;   // lower bound of dist
        const float gmax = __uint_as_float((unsigned)(key >> 32));
        const bool act = (lb <= 0.0f) || ((lb * lb) * 0.999f <= gmax);

        if (act) {
            // exact numpy distance: ((dx*dx+dy*dy)+dz*dz), each op rn, no fma
            u64 nk = 0;
            float nbx = px[0], nby = py[0], nbz = pz[0];
#pragma unroll
            for (int k = 0; k < GP; ++k) {
                const float dx = px[k] - cx;
                const float dy = py[k] - cy;
                const float dz = pz[k] - cz;
                const float d  = (dx * dx + dy * dy) + dz * dz;
                const float nd = fminf(dst[k], d);
                dst[k] = nd;
                const u64 c = ((u64)(unsigned)__float_as_uint(nd) << 32) | (unsigned)inv[k];
                if (c > nk) { nk = c; nbx = px[k]; nby = py[k]; nbz = pz[k]; }
            }
            key = nk; bx = nbx; by = nby; bz = nbz;
        }

        // ---- wave winner: value DPP-max, then fetch unique key ----
        const unsigned v  = (unsigned)(key >> 32);
        const unsigned mv = wave_max_u32(v);
        const u64 mm = __ballot(v == mv);
        u64 kw;
        if (__popcll(mm) == 1) {                     // wave-uniform branch
            kw = rdlane64(key, (int)(__ffsll((long long)mm) - 1));
        } else {                                     // bit-equal values (rare)
            u64 t = (v == mv) ? key : 0ull;
#pragma unroll
            for (int off = 32; off > 0; off >>= 1) {
                const u64 o = __shfl_xor(t, off);
                if (o > t) t = o;
            }
            kw = t;
        }
        const u64 mm2 = __ballot(key == kw);         // keys unique: 1 lane
        const int l0  = (int)(__ffsll((long long)mm2) - 1);
        const float wx = __int_as_float(__builtin_amdgcn_readlane(__float_as_int(bx), l0));
        const float wy = __int_as_float(__builtin_amdgcn_readlane(__float_as_int(by), l0));
        const float wz = __int_as_float(__builtin_amdgcn_readlane(__float_as_int(bz), l0));

        // ---- cross-wave: ONE barrier, double-buffered ----
        const int buf = (it + 1) & 1;
        if (lane == 0) {
            s_key[buf][wave] = kw;
            s_cx[buf][wave] = wx; s_cy[buf][wave] = wy; s_cz[buf][wave] = wz;
        }
        __syncthreads();
        u64 bk = s_key[buf][0];
        float ncx = s_cx[buf][0], ncy = s_cy[buf][0], ncz = s_cz[buf][0];
#pragma unroll
        for (int w = 1; w < NWAVE; ++w) {
            const u64 o = s_key[buf][w];
            const bool g = o > bk;
            bk  = g ? o : bk;
            ncx = g ? s_cx[buf][w] : ncx;
            ncy = g ? s_cy[buf][w] : ncy;
            ncz = g ? s_cz[buf][w] : ncz;
        }
        far = __builtin_amdgcn_readfirstlane((N_PTS - 1) - (int)(bk & 0xFFFFu));
        cx = ncx; cy = ncy; cz = ncz;                // winner coords from LDS
    }
}

// ---------------------------------------------------------------------------
// Fallback single-block FPS (round-2 kernel, known-good) if ws too small.
// ---------------------------------------------------------------------------
__device__ inline u64 pack_key1(float v, int idx) {
    return ((u64)__float_as_uint(v) << 32) | (unsigned)(N_PTS - 1 - idx);
}
__global__ __launch_bounds__(512, 2) void fps_single(
    const float* __restrict__ xyz, int* __restrict__ cent)
{
    constexpr int BL = 512, KP = N_PTS / BL, NW = BL / 64;
    const int b = blockIdx.x, tid = threadIdx.x;
    const float* X = xyz + (size_t)b * 3 * N_PTS;
    const float* Y = X + N_PTS;
    const float* Z = X + 2 * N_PTS;

    float px[KP], py[KP], pz[KP], dst[KP];
#pragma unroll
    for (int k = 0; k < KP; ++k) {
        const int p = tid + k * BL;
        px[k] = X[p]; py[k] = Y[p]; pz[k] = Z[p]; dst[k] = BIGF;
    }
    __shared__ u64 s_key[2][NW];
    const int wave = tid >> 6, lane = tid & 63;

    float bv = px[0]; int bi = tid;
#pragma unroll
    for (int k = 1; k < KP; ++k)
        if (px[k] > bv) { bv = px[k]; bi = tid + k * BL; }
    u64 key = pack_key1(bv, bi);
#pragma unroll
    for (int off = 32; off > 0; off >>= 1) {
        const u64 o = __shfl_xor(key, off);
        if (o > key) key = o;
    }
    if (lane == 0) s_key[0][wave] = key;
    __syncthreads();
    u64 bk = s_key[0][0];
#pragma unroll
    for (int w = 1; w < NW; ++w)
        if (s_key[0][w] > bk) bk = s_key[0][w];
    int far = __builtin_amdgcn_readfirstlane(N_PTS - 1 - (int)(bk & 0xFFFFu));

    for (int it = 0; it < NPOINT; ++it) {
        if (tid == 0) cent[b * NPOINT + it] = far;
        if (it == NPOINT - 1) break;
        const float cx = X[far], cy = Y[far], cz = Z[far];
        float nbv = -1.0f; int nbi = 0;
#pragma unroll
        for (int k = 0; k < KP; ++k) {
            const float dx = __fsub_rn(px[k], cx);
            const float dy = __fsub_rn(py[k], cy);
            const float dz = __fsub_rn(pz[k], cz);
            const float d  = __fadd_rn(
                __fadd_rn(__fmul_rn(dx, dx), __fmul_rn(dy, dy)),
                __fmul_rn(dz, dz));
            const float nd = fminf(dst[k], d);
            dst[k] = nd;
            if (nd > nbv) { nbv = nd; nbi = tid + k * BL; }
        }
        u64 k2 = pack_key1(nbv, nbi);
#pragma unroll
        for (int off = 32; off > 0; off >>= 1) {
            const u64 o = __shfl_xor(k2, off);
            if (o > k2) k2 = o;
        }
        const int buf = (it + 1) & 1;
        if (lane == 0) s_key[buf][wave] = k2;
        __syncthreads();
        u64 b2 = s_key[buf][0];
#pragma unroll
        for (int w = 1; w < NW; ++w)
            if (s_key[buf][w] > b2) b2 = s_key[buf][w];
        far = __builtin_amdgcn_readfirstlane(N_PTS - 1 - (int)(b2 & 0xFFFFu));
    }
}

// ---------------------------------------------------------------------------
// Ball query, nsample=1: one wave per centroid; scan 64-pt chunks from index
// 0, first hit wins. Distance = reference einsum ((-2*dot)+|c|^2)+|p|^2;
// keep-test d <= 0.25 (== !(d > r^2)).
// ---------------------------------------------------------------------------
__global__ __launch_bounds__(256) void ballq_kernel(
    const float* __restrict__ xyz,
    const int* __restrict__ cent,
    int* __restrict__ out)
{
    const int gw   = (blockIdx.x * 256 + threadIdx.x) >> 6;
    const int lane = threadIdx.x & 63;
    const int b = gw / NPOINT;
    const int s = gw % NPOINT;

    const float* X = xyz + (size_t)b * 3 * N_PTS;
    const float* Y = X + N_PTS;
    const float* Z = X + 2 * N_PTS;

    const int ci = cent[b * NPOINT + s];
    const float cx = X[ci], cy = Y[ci], cz = Z[ci];
    const float cn = __fadd_rn(
        __fadd_rn(__fmul_rn(cx, cx), __fmul_rn(cy, cy)), __fmul_rn(cz, cz));

    int res = N_PTS;
    for (int base = 0; base < N_PTS; base += 64) {
        const int p = base + lane;
        const float x = X[p], y = Y[p], z = Z[p];
        const float dot = __fadd_rn(
            __fadd_rn(__fmul_rn(x, cx), __fmul_rn(y, cy)), __fmul_rn(z, cz));
        const float pn = __fadd_rn(
            __fadd_rn(__fmul_rn(x, x), __fmul_rn(y, y)), __fmul_rn(z, z));
        const float d = __fadd_rn(__fadd_rn(__fmul_rn(-2.0f, dot), cn), pn);
        const u64 m = __ballot(!(d > 0.25f));
        if (m) {
            res = base + (__ffsll((long long)m) - 1);
            break;
        }
    }
    if (lane == 0) out[b * NPOINT + s] = res;
}

extern "C" void kernel_launch(void* const* d_in, const int* in_sizes, int n_in,
                              void* d_out, int out_size, void* d_ws, size_t ws_size,
                              hipStream_t stream) {
    const float* xyz = (const float*)d_in[0];
    const int B = in_sizes[1] / 16;            // cls_label is [B,16]
    int* out = (int*)d_out;

    const size_t permB = (size_t)B * N_PTS * sizeof(int);
    const size_t centB = (size_t)B * NPOINT * sizeof(int);

    if (ws_size >= permB + centB) {
        int* perm = (int*)d_ws;
        int* cent = (int*)((char*)d_ws + permB);
        bin_kernel<<<B, TB, 0, stream>>>(xyz, perm);
        fps_group<<<B, TB, 0, stream>>>(xyz, perm, cent);
        ballq_kernel<<<B * NPOINT / 4, 256, 0, stream>>>(xyz, cent, out);
    } else {
        int* cent = (ws_size >= centB) ? (int*)d_ws : out;  // alias-safe
        fps_single<<<B, 512, 0, stream>>>(xyz, cent);
        ballq_kernel<<<B * NPOINT / 4, 256, 0, stream>>>(xyz, cent, out);
    }
}